// Round 6
// baseline (102.773 us; speedup 1.0000x reference)
//
#include <hip/hip_runtime.h>
#include <math.h>

#define Tdim 1024
#define Hh   64

#if __has_builtin(__builtin_amdgcn_exp2f)
#define EXP2(x) __builtin_amdgcn_exp2f(x)
#else
#define EXP2(x) exp2f(x)
#endif

// (1/(sqrt(2)*0.8)) * log2(e) — folded into Q so attention uses exp2 directly
__device__ __constant__ float kQScale = 0.8838834764831844f * 1.4426950408889634f;

// ---------------------------------------------------------------------------
// Kernel 1: fused QKV projection, zero-LDS.
// Thread owns one x row in VGPRs (32 float4); W pointers are wave-uniform
// (blockIdx + loop constants) -> scalar s_load path; inner loop is pure
// v_fma_f32 with one SGPR operand. 8 cols/thread.
// grid = (8 row-blocks of 256, 16 col-groups of 8, 3 matrices), block = 256.
// Q written (B,T,D) pre-scaled by kQScale; K,V packed into KV float4
// (k0,k1,v0,v1) per (bh,t).
// ---------------------------------------------------------------------------
__global__ __launch_bounds__(256, 2) void qkv_proj(
    const float* __restrict__ x, const float* __restrict__ Wq,
    const float* __restrict__ Wk, const float* __restrict__ Wv,
    float* __restrict__ Q, float* __restrict__ KV)
{
    const int tid = threadIdx.x;
    const int row = blockIdx.x * 256 + tid;   // 0..2047
    const int jb  = blockIdx.y * 8;           // col base
    const int mat = blockIdx.z;               // 0=Q 1=K 2=V
    const float* __restrict__ W = (mat == 0) ? Wq : (mat == 1) ? Wk : Wv;

    // x row -> 32 float4 VGPRs
    float4 xr[32];
    {
        const float4* xrow = reinterpret_cast<const float4*>(x + (size_t)row * 128);
#pragma unroll
        for (int k = 0; k < 32; ++k) xr[k] = xrow[k];
    }

    float acc[8];
#pragma unroll
    for (int c = 0; c < 8; ++c) acc[c] = 0.f;

    // 8 independent fma chains; W loads are wave-uniform -> s_load
#pragma unroll
    for (int c = 0; c < 8; ++c) {
        const float4* wp = reinterpret_cast<const float4*>(W + (size_t)(jb + c) * 128);
        float a = 0.f;
#pragma unroll
        for (int k = 0; k < 32; ++k) {
            const float4 wv = wp[k];
            const float4 xv = xr[k];
            a = fmaf(xv.x, wv.x, fmaf(xv.y, wv.y, fmaf(xv.z, wv.z, fmaf(xv.w, wv.w, a))));
        }
        acc[c] = a;
    }

    const int b = row >> 10, t = row & 1023;
    if (mat == 0) {
        float4 o0 = make_float4(acc[0] * kQScale, acc[1] * kQScale,
                                acc[2] * kQScale, acc[3] * kQScale);
        float4 o1 = make_float4(acc[4] * kQScale, acc[5] * kQScale,
                                acc[6] * kQScale, acc[7] * kQScale);
        *reinterpret_cast<float4*>(Q + (size_t)row * 128 + jb)     = o0;
        *reinterpret_cast<float4*>(Q + (size_t)row * 128 + jb + 4) = o1;
    } else {
        const int off = (mat == 1) ? 0 : 2;
#pragma unroll
        for (int cc = 0; cc < 4; ++cc) {
            const int h = (jb >> 1) + cc;     // head for cols jb+2cc, jb+2cc+1
            *reinterpret_cast<float2*>(
                KV + (((size_t)(b * Hh + h) * Tdim + t) * 4 + off)) =
                make_float2(acc[2 * cc], acc[2 * cc + 1]);
        }
    }
}

// ---------------------------------------------------------------------------
// Kernel 2: causal attention, head_dim=2, single-pass no-max softmax in exp2
// domain. Balanced chunk pairing: block bx handles query chunks (c, 15-c);
// each thread owns 2 low + 2 high queries, 8 key sub-lanes -> every thread
// in every block performs exactly 240 query-key updates.
// grid = (8, B*H=128), block = 256.
// ---------------------------------------------------------------------------
__global__ __launch_bounds__(256) void attn(
    const float* __restrict__ Q, const float4* __restrict__ KV,
    float* __restrict__ O)
{
    __shared__ float4 KVs[Tdim];   // 16 KB
    const int tid   = threadIdx.x;
    const int c     = blockIdx.x;          // 0..7
    const int bh    = blockIdx.y;
    const int lowb  = c * 64;
    const int highb = (15 - c) * 64;
    const int nk    = highb + 64;          // keys needed: 0..nk-1

    const float4* KVg = KV + (size_t)bh * Tdim;
    for (int i = tid; i < nk; i += 256) KVs[i] = KVg[i];
    __syncthreads();

    const int sub = tid & 7;               // key sub-lane
    const int g   = tid >> 3;              // 0..31 query group
    const int lq  = lowb + g * 2;          // owns lq, lq+1
    const int hq  = highb + g * 2;         // owns hq, hq+1
    const int b   = bh >> 6, h = bh & 63;

    const float* Qb = Q + (size_t)b * (Tdim * 128) + h * 2;
    float2 q[4];
    q[0] = *reinterpret_cast<const float2*>(Qb + (size_t)(lq    ) * 128);
    q[1] = *reinterpret_cast<const float2*>(Qb + (size_t)(lq + 1) * 128);
    q[2] = *reinterpret_cast<const float2*>(Qb + (size_t)(hq    ) * 128);
    q[3] = *reinterpret_cast<const float2*>(Qb + (size_t)(hq + 1) * 128);

    float l[4]  = {0.f, 0.f, 0.f, 0.f};
    float a0[4] = {0.f, 0.f, 0.f, 0.f};
    float a1[4] = {0.f, 0.f, 0.f, 0.f};

    auto upd = [&](int i, const float4 kv) {
        const float p = EXP2(fmaf(q[i].x, kv.x, q[i].y * kv.y));
        l[i] += p;
        a0[i] = fmaf(p, kv.z, a0[i]);
        a1[i] = fmaf(p, kv.w, a1[i]);
    };

    // phase 1: keys [0, lq) at residue sub — all 4 queries
#pragma unroll 2
    for (int k = sub; k < lq; k += 8) {
        const float4 kv = KVs[k];
        upd(0, kv); upd(1, kv); upd(2, kv); upd(3, kv);
    }
    // low diagonal tail: key lq (queries lq, lq+1), key lq+1 (query lq+1)
    if (sub <= 1) {
        const float4 kv = KVs[lq + sub];
        if (sub == 0) upd(0, kv);
        upd(1, kv);
    }
    // phase 2: keys [lq.., hq) at residue sub — high queries only
    int k2 = (lq & ~7) + sub; if (k2 < lq) k2 += 8;
#pragma unroll 4
    for (int k = k2; k < hq; k += 8) {
        const float4 kv = KVs[k];
        upd(2, kv); upd(3, kv);
    }
    // high diagonal tail
    if (sub <= 1) {
        const float4 kv = KVs[hq + sub];
        if (sub == 0) upd(2, kv);
        upd(3, kv);
    }

    // reduce across 8 sub-lanes
#pragma unroll
    for (int i = 0; i < 4; ++i) {
        l[i]  += __shfl_xor(l[i], 1);  l[i]  += __shfl_xor(l[i], 2);  l[i]  += __shfl_xor(l[i], 4);
        a0[i] += __shfl_xor(a0[i], 1); a0[i] += __shfl_xor(a0[i], 2); a0[i] += __shfl_xor(a0[i], 4);
        a1[i] += __shfl_xor(a1[i], 1); a1[i] += __shfl_xor(a1[i], 2); a1[i] += __shfl_xor(a1[i], 4);
    }

    if (sub == 0) {
        float* Ob = O + (size_t)b * (Tdim * 128) + h * 2;
#pragma unroll
        for (int i = 0; i < 4; ++i) {
            const int row = (i < 2) ? (lq + i) : (hq + i - 2);
            const float rl = 1.0f / l[i];
            *reinterpret_cast<float2*>(Ob + (size_t)row * 128) =
                make_float2(a0[i] * rl, a1[i] * rl);
        }
    }
}

// ---------------------------------------------------------------------------
// Kernel 3: output projection out = O @ Wo.T, zero-LDS (same scheme as qkv).
// 4 cols/thread. grid = (8 row-blocks, 32 col-groups), block = 256.
// ---------------------------------------------------------------------------
__global__ __launch_bounds__(256, 2) void out_proj(
    const float* __restrict__ Oin, const float* __restrict__ Wo,
    float* __restrict__ out)
{
    const int tid = threadIdx.x;
    const int row = blockIdx.x * 256 + tid;
    const int jb  = blockIdx.y * 4;

    float4 xr[32];
    {
        const float4* xrow = reinterpret_cast<const float4*>(Oin + (size_t)row * 128);
#pragma unroll
        for (int k = 0; k < 32; ++k) xr[k] = xrow[k];
    }

    float acc[4];
#pragma unroll
    for (int c = 0; c < 4; ++c) acc[c] = 0.f;

#pragma unroll
    for (int c = 0; c < 4; ++c) {
        const float4* wp = reinterpret_cast<const float4*>(Wo + (size_t)(jb + c) * 128);
        float a = 0.f;
#pragma unroll
        for (int k = 0; k < 32; ++k) {
            const float4 wv = wp[k];
            const float4 xv = xr[k];
            a = fmaf(xv.x, wv.x, fmaf(xv.y, wv.y, fmaf(xv.z, wv.z, fmaf(xv.w, wv.w, a))));
        }
        acc[c] = a;
    }

    *reinterpret_cast<float4*>(out + (size_t)row * 128 + jb) =
        make_float4(acc[0], acc[1], acc[2], acc[3]);
}

extern "C" void kernel_launch(void* const* d_in, const int* in_sizes, int n_in,
                              void* d_out, int out_size, void* d_ws, size_t ws_size,
                              hipStream_t stream) {
    const float* x  = (const float*)d_in[0];
    const float* Wq = (const float*)d_in[1];
    const float* Wk = (const float*)d_in[2];
    const float* Wv = (const float*)d_in[3];
    const float* Wo = (const float*)d_in[4];
    float* out = (float*)d_out;

    // workspace: Q (B,T,D) 1MB | KV (B,H,T,4) 2MB | O (B,T,D) 1MB
    float* ws = (float*)d_ws;
    float* Q  = ws;
    float* KV = ws + 262144;
    float* O  = ws + 786432;

    qkv_proj<<<dim3(8, 16, 3), 256, 0, stream>>>(x, Wq, Wk, Wv, Q, KV);
    attn<<<dim3(8, 128), 256, 0, stream>>>(Q, (const float4*)KV, O);
    out_proj<<<dim3(8, 32), 256, 0, stream>>>(O, Wo, out);
}

// Round 7
// 98.615 us; speedup vs baseline: 1.0422x; 1.0422x over previous
//
#include <hip/hip_runtime.h>
#include <math.h>

#define Tdim 1024
#define Hh   64

#if __has_builtin(__builtin_amdgcn_exp2f)
#define EXP2(x) __builtin_amdgcn_exp2f(x)
#else
#define EXP2(x) exp2f(x)
#endif

// (1/(sqrt(2)*0.8)) * log2(e) — folded into Q so attention uses exp2 directly
__device__ __constant__ float kQScale = 0.8838834764831844f * 1.4426950408889634f;

// ---------------------------------------------------------------------------
// Kernel 1: fused QKV projection (R5 design, known-good).
// grid = (128 row-groups of 16, 3), block = 256.
// Q written (B,T,D) pre-scaled by kQScale; K,V packed into KV float4.
// ---------------------------------------------------------------------------
__global__ __launch_bounds__(256) void qkv_proj(
    const float* __restrict__ x, const float* __restrict__ Wq,
    const float* __restrict__ Wk, const float* __restrict__ Wv,
    float* __restrict__ Q, float* __restrict__ KV)
{
    __shared__ float xs[16][128];     // 8 KB
    __shared__ float Wch[128][36];    // 18 KB, 32-k chunk of W, pad->36

    const int tid  = threadIdx.x;
    const int row0 = blockIdx.x * 16;
    const int w    = blockIdx.y;      // 0=Q 1=K 2=V

    {
        const float4* xg = reinterpret_cast<const float4*>(x + (size_t)row0 * 128);
        reinterpret_cast<float4*>(&xs[0][0])[tid]       = xg[tid];
        reinterpret_cast<float4*>(&xs[0][0])[tid + 256] = xg[tid + 256];
    }

    const float* W = (w == 0) ? Wq : (w == 1) ? Wk : Wv;

    const int j0 = tid & 31;          // cols j0 + {0,32,64,96}
    const int r0 = (tid >> 5) << 1;   // rows r0, r0+1

    float acc[2][4];
#pragma unroll
    for (int r = 0; r < 2; ++r)
#pragma unroll
        for (int c = 0; c < 4; ++c) acc[r][c] = 0.f;

    for (int ch = 0; ch < 4; ++ch) {
        __syncthreads();
#pragma unroll
        for (int s = 0; s < 4; ++s) {
            const int idx  = tid + s * 256;   // 0..1023
            const int rowW = idx >> 3;
            const int c4   = idx & 7;
            *reinterpret_cast<float4*>(&Wch[rowW][c4 * 4]) =
                reinterpret_cast<const float4*>(W + (size_t)rowW * 128 + ch * 32)[c4];
        }
        __syncthreads();

#pragma unroll
        for (int c = 0; c < 8; ++c) {
            const float4 w0 = *reinterpret_cast<const float4*>(&Wch[j0      ][c * 4]);
            const float4 w1 = *reinterpret_cast<const float4*>(&Wch[j0 + 32 ][c * 4]);
            const float4 w2 = *reinterpret_cast<const float4*>(&Wch[j0 + 64 ][c * 4]);
            const float4 w3 = *reinterpret_cast<const float4*>(&Wch[j0 + 96 ][c * 4]);
#pragma unroll
            for (int r = 0; r < 2; ++r) {
                const float4 xv = *reinterpret_cast<const float4*>(&xs[r0 + r][ch * 32 + c * 4]);
                acc[r][0] = fmaf(xv.x, w0.x, fmaf(xv.y, w0.y, fmaf(xv.z, w0.z, fmaf(xv.w, w0.w, acc[r][0]))));
                acc[r][1] = fmaf(xv.x, w1.x, fmaf(xv.y, w1.y, fmaf(xv.z, w1.z, fmaf(xv.w, w1.w, acc[r][1]))));
                acc[r][2] = fmaf(xv.x, w2.x, fmaf(xv.y, w2.y, fmaf(xv.z, w2.z, fmaf(xv.w, w2.w, acc[r][2]))));
                acc[r][3] = fmaf(xv.x, w3.x, fmaf(xv.y, w3.y, fmaf(xv.z, w3.z, fmaf(xv.w, w3.w, acc[r][3]))));
            }
        }
    }

#pragma unroll
    for (int r = 0; r < 2; ++r) {
        const int row = row0 + r0 + r;
        const int bb  = row >> 10;
        const int t   = row & 1023;
#pragma unroll
        for (int jj = 0; jj < 4; ++jj) {
            const int j = j0 + jj * 32;
            const float v = acc[r][jj];
            if (w == 0) {
                Q[(size_t)row * 128 + j] = v * kQScale;
            } else {
                const int h  = j >> 1, dh = j & 1;
                const int bh = bb * Hh + h;
                KV[((size_t)bh * Tdim + t) * 4 + ((w == 1) ? dh : 2 + dh)] = v;
            }
        }
    }
}

// ---------------------------------------------------------------------------
// Kernel 2: causal attention, head_dim=2, single-pass no-max softmax (exp2).
// Balanced pairing: block bx handles query chunks (c, 15-c); thread owns
// 4 low + 4 high queries with swapped high assignment (lq+hq = 1020 const),
// 16 key sub-lanes -> half the ds_read_b128 of the 8-sublane version.
// grid = (8, B*H=128), block = 256.
// ---------------------------------------------------------------------------
__global__ __launch_bounds__(256) void attn(
    const float* __restrict__ Q, const float4* __restrict__ KV,
    float* __restrict__ O)
{
    __shared__ float4 KVs[Tdim];   // 16 KB
    const int tid   = threadIdx.x;
    const int c     = blockIdx.x;          // 0..7
    const int bh    = blockIdx.y;
    const int lowb  = c * 64;
    const int highb = (15 - c) * 64;
    const int nk    = highb + 64;          // keys needed: 0..nk-1

    const float4* KVg = KV + (size_t)bh * Tdim;
    for (int i = tid; i < nk; i += 256) KVs[i] = KVg[i];
    __syncthreads();

    const int sub = tid & 15;              // key sub-lane (16)
    const int g   = tid >> 4;              // 0..15 query group
    const int lq  = lowb + g * 4;          // low queries lq..lq+3
    const int hq  = highb + (60 - g * 4);  // high queries hq..hq+3 (balance swap)
    const int b   = bh >> 6, h = bh & 63;

    const float* Qb = Q + (size_t)b * (Tdim * 128) + h * 2;
    float2 q[8];
#pragma unroll
    for (int i = 0; i < 4; ++i) {
        q[i]     = *reinterpret_cast<const float2*>(Qb + (size_t)(lq + i) * 128);
        q[4 + i] = *reinterpret_cast<const float2*>(Qb + (size_t)(hq + i) * 128);
    }

    float l[8], a0[8], a1[8];
#pragma unroll
    for (int i = 0; i < 8; ++i) { l[i] = 0.f; a0[i] = 0.f; a1[i] = 0.f; }

    auto upd = [&](int i, const float4 kv) {
        const float p = EXP2(fmaf(q[i].x, kv.x, q[i].y * kv.y));
        l[i] += p;
        a0[i] = fmaf(p, kv.z, a0[i]);
        a1[i] = fmaf(p, kv.w, a1[i]);
    };

    // phase 1: keys [0, lq) — all 8 queries
#pragma unroll 2
    for (int k = sub; k < lq; k += 16) {
        const float4 kv = KVs[k];
        upd(0, kv); upd(1, kv); upd(2, kv); upd(3, kv);
        upd(4, kv); upd(5, kv); upd(6, kv); upd(7, kv);
    }
    // low diagonal: keys lq..lq+3 (low queries causal, high queries full)
    if (sub < 4) {
        const float4 kv = KVs[lq + sub];
        if (sub == 0) upd(0, kv);
        if (sub <= 1) upd(1, kv);
        if (sub <= 2) upd(2, kv);
        upd(3, kv);
        upd(4, kv); upd(5, kv); upd(6, kv); upd(7, kv);
    }
    // phase 2: keys [lq+4, hq) — high queries only
    int k2 = (lq & ~15) + sub;
    if (k2 < lq + 4) k2 += 16;
#pragma unroll 2
    for (int k = k2; k < hq; k += 16) {
        const float4 kv = KVs[k];
        upd(4, kv); upd(5, kv); upd(6, kv); upd(7, kv);
    }
    // high diagonal: keys hq..hq+3
    if (sub < 4) {
        const float4 kv = KVs[hq + sub];
        if (sub == 0) upd(4, kv);
        if (sub <= 1) upd(5, kv);
        if (sub <= 2) upd(6, kv);
        upd(7, kv);
    }

    // reduce across 16 sub-lanes
#pragma unroll
    for (int i = 0; i < 8; ++i) {
        l[i]  += __shfl_xor(l[i], 1);  l[i]  += __shfl_xor(l[i], 2);
        l[i]  += __shfl_xor(l[i], 4);  l[i]  += __shfl_xor(l[i], 8);
        a0[i] += __shfl_xor(a0[i], 1); a0[i] += __shfl_xor(a0[i], 2);
        a0[i] += __shfl_xor(a0[i], 4); a0[i] += __shfl_xor(a0[i], 8);
        a1[i] += __shfl_xor(a1[i], 1); a1[i] += __shfl_xor(a1[i], 2);
        a1[i] += __shfl_xor(a1[i], 4); a1[i] += __shfl_xor(a1[i], 8);
    }

    if (sub == 0) {
        float* Ob = O + (size_t)b * (Tdim * 128) + h * 2;
#pragma unroll
        for (int i = 0; i < 8; ++i) {
            const int row = (i < 4) ? (lq + i) : (hq + i - 4);
            const float rl = 1.0f / l[i];
            *reinterpret_cast<float2*>(Ob + (size_t)row * 128) =
                make_float2(a0[i] * rl, a1[i] * rl);
        }
    }
}

// ---------------------------------------------------------------------------
// Kernel 3: output projection out = O @ Wo.T (R5 design, known-good).
// grid = 128, block = 256.
// ---------------------------------------------------------------------------
__global__ __launch_bounds__(256) void out_proj(
    const float* __restrict__ Oin, const float* __restrict__ Wo,
    float* __restrict__ out)
{
    __shared__ float xs[16][128];
    __shared__ float Wch[128][36];

    const int tid  = threadIdx.x;
    const int row0 = blockIdx.x * 16;

    {
        const float4* xg = reinterpret_cast<const float4*>(Oin + (size_t)row0 * 128);
        reinterpret_cast<float4*>(&xs[0][0])[tid]       = xg[tid];
        reinterpret_cast<float4*>(&xs[0][0])[tid + 256] = xg[tid + 256];
    }

    const int j0 = tid & 31;
    const int r0 = (tid >> 5) << 1;

    float acc[2][4];
#pragma unroll
    for (int r = 0; r < 2; ++r)
#pragma unroll
        for (int c = 0; c < 4; ++c) acc[r][c] = 0.f;

    for (int ch = 0; ch < 4; ++ch) {
        __syncthreads();
#pragma unroll
        for (int s = 0; s < 4; ++s) {
            const int idx  = tid + s * 256;
            const int rowW = idx >> 3;
            const int c4   = idx & 7;
            *reinterpret_cast<float4*>(&Wch[rowW][c4 * 4]) =
                reinterpret_cast<const float4*>(Wo + (size_t)rowW * 128 + ch * 32)[c4];
        }
        __syncthreads();

#pragma unroll
        for (int c = 0; c < 8; ++c) {
            const float4 w0 = *reinterpret_cast<const float4*>(&Wch[j0      ][c * 4]);
            const float4 w1 = *reinterpret_cast<const float4*>(&Wch[j0 + 32 ][c * 4]);
            const float4 w2 = *reinterpret_cast<const float4*>(&Wch[j0 + 64 ][c * 4]);
            const float4 w3 = *reinterpret_cast<const float4*>(&Wch[j0 + 96 ][c * 4]);
#pragma unroll
            for (int r = 0; r < 2; ++r) {
                const float4 xv = *reinterpret_cast<const float4*>(&xs[r0 + r][ch * 32 + c * 4]);
                acc[r][0] = fmaf(xv.x, w0.x, fmaf(xv.y, w0.y, fmaf(xv.z, w0.z, fmaf(xv.w, w0.w, acc[r][0]))));
                acc[r][1] = fmaf(xv.x, w1.x, fmaf(xv.y, w1.y, fmaf(xv.z, w1.z, fmaf(xv.w, w1.w, acc[r][1]))));
                acc[r][2] = fmaf(xv.x, w2.x, fmaf(xv.y, w2.y, fmaf(xv.z, w2.z, fmaf(xv.w, w2.w, acc[r][2]))));
                acc[r][3] = fmaf(xv.x, w3.x, fmaf(xv.y, w3.y, fmaf(xv.z, w3.z, fmaf(xv.w, w3.w, acc[r][3]))));
            }
        }
    }

#pragma unroll
    for (int r = 0; r < 2; ++r) {
        const int row = row0 + r0 + r;
#pragma unroll
        for (int jj = 0; jj < 4; ++jj) {
            const int j = j0 + jj * 32;
            out[(size_t)row * 128 + j] = acc[r][jj];
        }
    }
}

extern "C" void kernel_launch(void* const* d_in, const int* in_sizes, int n_in,
                              void* d_out, int out_size, void* d_ws, size_t ws_size,
                              hipStream_t stream) {
    const float* x  = (const float*)d_in[0];
    const float* Wq = (const float*)d_in[1];
    const float* Wk = (const float*)d_in[2];
    const float* Wv = (const float*)d_in[3];
    const float* Wo = (const float*)d_in[4];
    float* out = (float*)d_out;

    // workspace: Q (B,T,D) 1MB | KV (B,H,T,4) 2MB | O (B,T,D) 1MB
    float* ws = (float*)d_ws;
    float* Q  = ws;
    float* KV = ws + 262144;
    float* O  = ws + 786432;

    qkv_proj<<<dim3(128, 3), 256, 0, stream>>>(x, Wq, Wk, Wv, Q, KV);
    attn<<<dim3(8, 128), 256, 0, stream>>>(Q, (const float4*)KV, O);
    out_proj<<<128, 256, 0, stream>>>(O, Wo, out);
}